// Round 3
// baseline (23871.317 us; speedup 1.0000x reference)
//
#include <hip/hip_runtime.h>
#include <stdint.h>

#define DEPTH 512
#define INSZ  256
#define SSZ   4096
#define NBLK  256      // one block per CU (<=1 block/CU resources => all resident)
#define NTHR  512      // 8 waves
#define RPB   16       // rows per block

typedef unsigned int  u32;
typedef unsigned short u16;
typedef __attribute__((ext_vector_type(8))) short bf16x8;
typedef __attribute__((ext_vector_type(4))) float f32x4;

__device__ __forceinline__ u32 f2bf_rne(float f) {
    u32 u = __float_as_uint(f);
    return (u + 0x7fffu + ((u >> 16) & 1u)) >> 16;   // RNE (finite inputs)
}
__device__ __forceinline__ float bf2f(u16 h) { return __uint_as_float(((u32)h) << 16); }

// ---------- init: build curA (hi planes 0..7, lo planes 8..15) + zero barrier ----------
__global__ __launch_bounds__(256) void init_misc(const float* __restrict__ state,
                                                 u16* __restrict__ curA,
                                                 u32* __restrict__ bar) {
    int idx = blockIdx.x * 256 + threadIdx.x;       // 256 blocks -> 65536 threads
    if (idx < 16 * SSZ) {
        int c = idx >> 12, k = idx & (SSZ - 1);
        float s = state[k];
        u16 hi = (u16)f2bf_rne(s);
        u16 v = (c >= 8) ? (u16)f2bf_rne(s - bf2f(hi)) : hi;
        curA[idx] = v;
    }
    if (idx < 64) bar[idx] = 0;
}

// ---------- biases[n][i] = sum_j W_in[i][j] * seq[n][j]  (f32) ----------
__global__ __launch_bounds__(256) void bias_kernel(const float* __restrict__ W_in,
                                                   const float* __restrict__ seq,
                                                   float* __restrict__ biases) {
    __shared__ float s_w[32][257];
    __shared__ float s_seq[8][260];
    const int i0 = blockIdx.x * 32;
    const int n0 = blockIdx.y * 8;
    const int tid = threadIdx.x;

    for (int idx = tid; idx < 32 * 256; idx += 256) {
        int r = idx >> 8, j = idx & 255;
        s_w[r][j] = W_in[(i0 + r) * INSZ + j];
    }
    for (int idx = tid; idx < 8 * 256; idx += 256) {
        int r = idx >> 8, j = idx & 255;
        s_seq[r][j] = seq[(n0 + r) * INSZ + j];
    }
    __syncthreads();

    const int i_loc = tid >> 3, n_loc = tid & 7;
    float acc = 0.f;
    #pragma unroll 8
    for (int j = 0; j < 256; ++j)
        acc = fmaf(s_w[i_loc][j], s_seq[n_loc][j], acc);
    biases[(size_t)(n0 + n_loc) * SSZ + i0 + i_loc] = acc;
}

// ---------- persistent recurrence kernel (plain launch, manual grid barrier) ----------
__global__ __launch_bounds__(NTHR, 2) void net_persistent(
        const float* __restrict__ W,        // (4096,4096) f32
        const float* __restrict__ biases,   // (512,4096) f32
        u16* __restrict__ curA,             // (16,4096) bf16 bits
        u16* __restrict__ curB,             // ping-pong partner
        const float* __restrict__ scales,   // (8,)
        float* __restrict__ out,            // (8,512,4096) f32
        u32* __restrict__ bar) {
    __shared__ float red[8][256];           // 8 KB only
    const int tid = threadIdx.x, bid = blockIdx.x;
    const int w = tid >> 6, l = tid & 63;
    const int r0 = bid * RPB;

    // ---- load this block's W rows as MFMA A-fragments into registers (one-time) ----
    // lane l: row = r0 + (l&15); k = w*512 + kt*32 + (l>>4)*8 + e  (e = 0..7 contiguous)
    bf16x8 afr[16];
    {
        const float* wp = W + (size_t)(r0 + (l & 15)) * SSZ + w * 512 + ((l >> 4) * 8);
        #pragma unroll
        for (int kt = 0; kt < 16; ++kt) {
            float4 x = *reinterpret_cast<const float4*>(wp + kt * 32);
            float4 y = *reinterpret_cast<const float4*>(wp + kt * 32 + 4);
            union { bf16x8 v; u32 u[4]; } pk;
            pk.u[0] = (f2bf_rne(x.y) << 16) | f2bf_rne(x.x);
            pk.u[1] = (f2bf_rne(x.w) << 16) | f2bf_rne(x.z);
            pk.u[2] = (f2bf_rne(y.y) << 16) | f2bf_rne(y.x);
            pk.u[3] = (f2bf_rne(y.w) << 16) | f2bf_rne(y.z);
            afr[kt] = pk.v;
        }
    }

    // B-operand base: lane l -> col c = l&15 (plane), k-group kg = l>>4
    const int c = l & 15, kg = l >> 4;
    const int boff = c * SSZ + w * 512 + kg * 8;
    const u16* bA = curA + boff;
    const u16* bB = curB + boff;

    // epilogue mapping (D: col = lane&15, row = (lane>>4)*4 + reg)
    const int e = tid, lane_e = e >> 2, reg = e & 3;
    const int col = lane_e & 15;
    const int row_l = ((lane_e >> 4) << 2) | reg;
    const bool act = (tid < 256) && (col < 8);
    const int grow = r0 + row_l;
    const float mysc = act ? scales[col] : 0.f;
    const float* bias_p = biases + grow;
    float* out_p = out + (((size_t)col) << 21) + grow;
    u16* hiA = curA + col * SSZ + grow;  u16* loA = curA + (col + 8) * SSZ + grow;
    u16* hiB = curB + col * SSZ + grow;  u16* loB = curB + (col + 8) * SSZ + grow;

    for (int t = 0; t < DEPTH; ++t) {
        const u16* bp = (t & 1) ? bB : bA;                    // read buffer
        float bias_v = act ? bias_p[(size_t)t << 12] : 0.f;   // early issue

        bf16x8 bfr[16];
        #pragma unroll
        for (int kt = 0; kt < 16; ++kt)
            bfr[kt] = *reinterpret_cast<const bf16x8*>(bp + kt * 32);

        f32x4 acc = {0.f, 0.f, 0.f, 0.f};
        #pragma unroll
        for (int kt = 0; kt < 16; ++kt)
            acc = __builtin_amdgcn_mfma_f32_16x16x32_bf16(afr[kt], bfr[kt], acc, 0, 0, 0);

        *reinterpret_cast<f32x4*>(&red[w][l * 4]) = acc;
        __syncthreads();

        if (act) {
            float d = 0.f;                      // hi-plane + lo-plane partials, all waves
            #pragma unroll
            for (int ww = 0; ww < 8; ++ww)
                d += red[ww][e] + red[ww][e + 32];
            float pre = fmaf(mysc, d, bias_v);
            float o = erff(pre) * 0.015625f;    // * 1/sqrt(4096)
            out_p[(size_t)t << 12] = o;
            u16 hi = (u16)f2bf_rne(o);
            u16 lo = (u16)f2bf_rne(o - bf2f(hi));
            u16* hp = (t & 1) ? hiA : hiB;      // write the OTHER buffer
            u16* lp = (t & 1) ? loA : loB;
            hp[0] = hi; lp[0] = lo;
        }

        if (t != DEPTH - 1) {
            if (tid < 256) __threadfence();     // release: drain + write back cur stores
            __syncthreads();                    // (also orders red reads before next write)
            if (tid == 0) {
                __hip_atomic_fetch_add(bar, 1u, __ATOMIC_ACQ_REL,
                                       __HIP_MEMORY_SCOPE_AGENT);
                const u32 target = (u32)NBLK * (u32)(t + 1);
                int guard = 0;
                while (__hip_atomic_load(bar, __ATOMIC_ACQUIRE,
                                         __HIP_MEMORY_SCOPE_AGENT) < target) {
                    __builtin_amdgcn_s_sleep(4);
                    if (++guard > (1 << 15)) break;   // never hang the container
                }
                __threadfence();                // acquire: invalidate L1/L2
            }
            __syncthreads();
        }
    }
}

// ---------- launch ----------
extern "C" void kernel_launch(void* const* d_in, const int* in_sizes, int n_in,
                              void* d_out, int out_size, void* d_ws, size_t ws_size,
                              hipStream_t stream) {
    const float* seq    = (const float*)d_in[0];   // (512, 256)
    const float* state  = (const float*)d_in[1];   // (4096,)
    const float* W_in   = (const float*)d_in[2];   // (4096, 256)
    const float* W_lin  = (const float*)d_in[3];   // (4096, 4096)
    const float* scales = (const float*)d_in[4];   // (8,)
    float* out = (float*)d_out;                    // (8, 512, 4096) f32

    char* ws = (char*)d_ws;
    u16*   curA   = (u16*)(ws);                    // 131072 B
    u16*   curB   = (u16*)(ws + 131072);           // 131072 B
    u32*   bar    = (u32*)(ws + 262144);           //    256 B
    float* biases = (float*)(ws + 327680);         //  8 MB

    init_misc<<<256, 256, 0, stream>>>(state, curA, bar);
    bias_kernel<<<dim3(128, 64), 256, 0, stream>>>(W_in, seq, biases);

    net_persistent<<<NBLK, NTHR, 0, stream>>>(W_lin, biases, curA, curB,
                                              scales, out, bar);
}

// Round 4
// 3573.135 us; speedup vs baseline: 6.6808x; 6.6808x over previous
//
#include <hip/hip_runtime.h>
#include <stdint.h>

#define DEPTH 512
#define INSZ  256
#define SSZ   4096
#define NBLK  256      // one block per CU -> all blocks resident
#define NTHR  512      // 8 waves
#define RPB   16       // rows per block

typedef unsigned int  u32;
typedef unsigned short u16;
typedef __attribute__((ext_vector_type(8))) short bf16x8;
typedef __attribute__((ext_vector_type(4))) float f32x4;

__device__ __forceinline__ u32 f2bf_rne(float f) {
    u32 u = __float_as_uint(f);
    return (u + 0x7fffu + ((u >> 16) & 1u)) >> 16;   // RNE (finite inputs)
}
__device__ __forceinline__ float bf2f(u16 h) { return __uint_as_float(((u32)h) << 16); }

// coherent (L1/L2-bypass, Infinity-Cache-served) accesses
__device__ __forceinline__ uint4 load_b128_cc(const void* p) {
    uint4 r;
    asm volatile("global_load_dwordx4 %0, %1, off sc0 sc1"
                 : "=v"(r) : "v"(p) : "memory");
    return r;
}
__device__ __forceinline__ void store_b32_cc(void* p, u32 v) {
    asm volatile("global_store_dword %0, %1, off sc0 sc1"
                 :: "v"(p), "v"(v) : "memory");
}

// ---------- init: build curA (hi planes 0..7, lo planes 8..15) + zero barrier ----------
__global__ __launch_bounds__(256) void init_misc(const float* __restrict__ state,
                                                 u16* __restrict__ curA,
                                                 u32* __restrict__ bar) {
    int idx = blockIdx.x * 256 + threadIdx.x;       // 65536 threads
    if (idx < 16 * SSZ) {
        int c = idx >> 12, k = idx & (SSZ - 1);
        float s = state[k];
        u16 hi = (u16)f2bf_rne(s);
        u16 v = (c >= 8) ? (u16)f2bf_rne(s - bf2f(hi)) : hi;
        curA[idx] = v;
    }
    if (idx < 512) bar[idx] = 0;
}

// ---------- biases[n][i] = sum_j W_in[i][j] * seq[n][j]  (f32) ----------
__global__ __launch_bounds__(256) void bias_kernel(const float* __restrict__ W_in,
                                                   const float* __restrict__ seq,
                                                   float* __restrict__ biases) {
    __shared__ float s_w[32][257];
    __shared__ float s_seq[8][260];
    const int i0 = blockIdx.x * 32;
    const int n0 = blockIdx.y * 8;
    const int tid = threadIdx.x;

    for (int idx = tid; idx < 32 * 256; idx += 256) {
        int r = idx >> 8, j = idx & 255;
        s_w[r][j] = W_in[(i0 + r) * INSZ + j];
    }
    for (int idx = tid; idx < 8 * 256; idx += 256) {
        int r = idx >> 8, j = idx & 255;
        s_seq[r][j] = seq[(n0 + r) * INSZ + j];
    }
    __syncthreads();

    const int i_loc = tid >> 3, n_loc = tid & 7;
    float acc = 0.f;
    #pragma unroll 8
    for (int j = 0; j < 256; ++j)
        acc = fmaf(s_w[i_loc][j], s_seq[n_loc][j], acc);
    biases[(size_t)(n0 + n_loc) * SSZ + i0 + i_loc] = acc;
}

// ---------- persistent recurrence kernel (relaxed-atomic grid barrier) ----------
__global__ __launch_bounds__(NTHR, 2) void net_persistent(
        const float* __restrict__ W,        // (4096,4096) f32
        const float* __restrict__ biases,   // (512,4096) f32
        u16* __restrict__ curA,             // (16,4096) bf16 bits: planes 0-7 hi, 8-15 lo
        u16* __restrict__ curB,             // ping-pong partner
        const float* __restrict__ scales,   // (8,)
        float* __restrict__ out,            // (8,512,4096) f32
        u32* __restrict__ bar) {            // leaves bar[g*32] g<8, root bar[256]
    __shared__ float red[8][256];           // 8 KB
    const int tid = threadIdx.x, bid = blockIdx.x;
    const int w = tid >> 6, l = tid & 63;
    const int r0 = bid * RPB;

    // ---- one-time: this block's W rows as MFMA A-fragments in registers ----
    // lane l: row = r0 + (l&15); k = w*512 + kt*32 + (l>>4)*8 + e
    bf16x8 afr[16];
    {
        const float* wp = W + (size_t)(r0 + (l & 15)) * SSZ + w * 512 + ((l >> 4) * 8);
        #pragma unroll
        for (int kt = 0; kt < 16; ++kt) {
            float4 x = *reinterpret_cast<const float4*>(wp + kt * 32);
            float4 y = *reinterpret_cast<const float4*>(wp + kt * 32 + 4);
            union { bf16x8 v; u32 u[4]; } pk;
            pk.u[0] = (f2bf_rne(x.y) << 16) | f2bf_rne(x.x);
            pk.u[1] = (f2bf_rne(x.w) << 16) | f2bf_rne(x.z);
            pk.u[2] = (f2bf_rne(y.y) << 16) | f2bf_rne(y.x);
            pk.u[3] = (f2bf_rne(y.w) << 16) | f2bf_rne(y.z);
            afr[kt] = pk.v;
        }
    }

    // B-operand addressing: lane -> plane c = l&15, k-group kg = l>>4
    const int c = l & 15, kg = l >> 4;
    const int boff = (c << 12) + w * 512 + (kg << 3);   // u16 index

    // ---- epilogue mapping: 64 writer threads, each owns (col, row-pair) ----
    // D frag: col = lane&15, row = (lane>>4)*4 + reg; red[w][lane*4+reg]
    // => red index(row_local, col) = ((row>>2)*16 + col)*4 + (row&3)
    const int j = tid;                 // writer id (j < 64 active)
    const int col = j & 7, pr = j >> 3;
    const int rl0 = 2 * pr, rl1 = 2 * pr + 1;
    const int idx0 = ((rl0 >> 2) * 16 + col) * 4 + (rl0 & 3);
    const int idx1 = ((rl1 >> 2) * 16 + col) * 4 + (rl1 & 3);
    const int gr0 = r0 + rl0;          // global even row
    const float mysc = scales[col];
    u32* nxA32 = reinterpret_cast<u32*>(curA);
    u32* nxB32 = reinterpret_cast<u32*>(curB);
    const int hiw = (col << 11) + (gr0 >> 1);          // u32 index in hi plane
    const int low = ((col + 8) << 11) + (gr0 >> 1);    // u32 index in lo plane

    u32* leafp = bar + ((bid >> 5) << 5);   // 8 leaves, 128 B apart
    u32* rootp = bar + 256;

    for (int t = 0; t < DEPTH; ++t) {
        const u16* bp = (t & 1) ? curB : curA;     // read buffer
        u32* np32 = (t & 1) ? nxA32 : nxB32;       // write buffer (the other one)

        float2 bv = {0.f, 0.f};
        if (j < 64) bv = *reinterpret_cast<const float2*>(
                             biases + ((size_t)t << 12) + gr0);

        // coherent B loads (bypass L1/L2 -> IF$), 16 x 16B per thread
        union { uint4 u4; bf16x8 v; } bfr[16];
        const u16* bbase = bp + boff;
        #pragma unroll
        for (int kt = 0; kt < 16; ++kt)
            bfr[kt].u4 = load_b128_cc(bbase + kt * 32);

        asm volatile("s_waitcnt vmcnt(0)" ::: "memory");
        __builtin_amdgcn_sched_barrier(0);

        f32x4 acc = {0.f, 0.f, 0.f, 0.f};
        #pragma unroll
        for (int kt = 0; kt < 16; ++kt)
            acc = __builtin_amdgcn_mfma_f32_16x16x32_bf16(afr[kt], bfr[kt].v, acc, 0, 0, 0);

        *reinterpret_cast<f32x4*>(&red[w][l * 4]) = acc;
        __syncthreads();

        if (j < 64) {
            float d0 = 0.f, d1 = 0.f;       // hi-plane + lo-plane partials, all waves
            #pragma unroll
            for (int ww = 0; ww < 8; ++ww) {
                d0 += red[ww][idx0] + red[ww][idx0 + 32];
                d1 += red[ww][idx1] + red[ww][idx1 + 32];
            }
            float pre0 = fmaf(mysc, d0, bv.x);
            float pre1 = fmaf(mysc, d1, bv.y);
            float o0 = erff(pre0) * 0.015625f;   // * 1/sqrt(4096)
            float o1 = erff(pre1) * 0.015625f;
            float2 ov; ov.x = o0; ov.y = o1;
            *reinterpret_cast<float2*>(out + ((size_t)col << 21)
                                           + ((size_t)t << 12) + gr0) = ov;
            u32 h0 = f2bf_rne(o0), h1 = f2bf_rne(o1);
            u32 l0 = f2bf_rne(o0 - bf2f((u16)h0));
            u32 l1 = f2bf_rne(o1 - bf2f((u16)h1));
            store_b32_cc(np32 + hiw, h0 | (h1 << 16));   // write-through to IF$
            store_b32_cc(np32 + low, l0 | (l1 << 16));
            asm volatile("s_waitcnt vmcnt(0)" ::: "memory");   // acked before barrier
        }
        __syncthreads();   // all stores drained block-wide

        if (t != DEPTH - 1) {
            if (tid == 0) {
                // fence-free 2-level barrier: RELAXED atomics only
                u32 old = __hip_atomic_fetch_add(leafp, 1u, __ATOMIC_RELAXED,
                                                 __HIP_MEMORY_SCOPE_AGENT);
                if ((old & 31u) == 31u)
                    __hip_atomic_fetch_add(rootp, 1u, __ATOMIC_RELAXED,
                                           __HIP_MEMORY_SCOPE_AGENT);
                const u32 tgt = 8u * (u32)(t + 1);
                int guard = 0;
                while (__hip_atomic_load(rootp, __ATOMIC_RELAXED,
                                         __HIP_MEMORY_SCOPE_AGENT) < tgt) {
                    __builtin_amdgcn_s_sleep(2);
                    if (++guard > (1 << 13)) break;   // never hang the container
                }
            }
            __syncthreads();
        }
    }
}

// ---------- launch ----------
extern "C" void kernel_launch(void* const* d_in, const int* in_sizes, int n_in,
                              void* d_out, int out_size, void* d_ws, size_t ws_size,
                              hipStream_t stream) {
    const float* seq    = (const float*)d_in[0];   // (512, 256)
    const float* state  = (const float*)d_in[1];   // (4096,)
    const float* W_in   = (const float*)d_in[2];   // (4096, 256)
    const float* W_lin  = (const float*)d_in[3];   // (4096, 4096)
    const float* scales = (const float*)d_in[4];   // (8,)
    float* out = (float*)d_out;                    // (8, 512, 4096) f32

    char* ws = (char*)d_ws;
    u16*   curA   = (u16*)(ws);                    // 131072 B
    u16*   curB   = (u16*)(ws + 131072);           // 131072 B
    u32*   bar    = (u32*)(ws + 262144);           //   4096 B
    float* biases = (float*)(ws + 266240);         //   8 MB

    init_misc<<<256, 256, 0, stream>>>(state, curA, bar);
    bias_kernel<<<dim3(128, 64), 256, 0, stream>>>(W_in, seq, biases);

    net_persistent<<<NBLK, NTHR, 0, stream>>>(W_lin, biases, curA, curB,
                                              scales, out, bar);
}